// Round 2
// baseline (147.473 us; speedup 1.0000x reference)
//
#include <hip/hip_runtime.h>

typedef __bf16 bf16;
typedef __bf16 bf16x4 __attribute__((ext_vector_type(4)));
typedef __bf16 bf16x8 __attribute__((ext_vector_type(8)));
typedef float  f32x4  __attribute__((ext_vector_type(4)));
typedef _Float16 f16;
typedef f16 f16x4 __attribute__((ext_vector_type(4)));

#define S_LEN 2048
#define D_DIM 1024
#define NHEAD 16
#define DHEAD 64
#define NPAR 2   // split-K x2; Q-tile 128 (8-wave blocks)

// ---------------------------------------------------------------------------
// async global->LDS, 16B per lane (wave-uniform LDS base + lane*16, m104).
__device__ __forceinline__ void async_cp16(const bf16* g, bf16* l) {
  __builtin_amdgcn_global_load_lds(
      (__attribute__((address_space(1))) void*)(void*)g,
      (__attribute__((address_space(3))) void*)l,
      16, 0, 0);
}

// ---------------------------------------------------------------------------
// fp32 -> bf16 cvt of x + 4 weights (blocks [0,3072)); block 3072 computes
// per-Q-tile key-block ranges kbr[32][2] from sorted seg_ids.
__global__ __launch_bounds__(256) void cvt_k(
    const float* __restrict__ x,  const float* __restrict__ w0,
    const float* __restrict__ w1, const float* __restrict__ w2,
    const float* __restrict__ w3, bf16* __restrict__ dst,
    const int* __restrict__ seg, int* __restrict__ kbr)
{
  __shared__ int firstv[4];
  const int b = blockIdx.x;
  const int t = threadIdx.x;

  if (b < 3072) {
    int i = b * 256 + t;  // 0 .. 786431 (x8 elems)
    const float* src;
    int off;
    if (i < (1 << 18)) {            // x: 2^18 groups of 8
      src = x; off = i;
    } else {
      int j = i - (1 << 18);        // weights: 2^17 groups each
      int s = j >> 17;
      off = j & ((1 << 17) - 1);
      src = (s == 0) ? w0 : (s == 1) ? w1 : (s == 2) ? w2 : w3;
    }
    f32x4 a = *(const f32x4*)(src + (size_t)off * 8);
    f32x4 bb = *(const f32x4*)(src + (size_t)off * 8 + 4);
    bf16x8 o;
    o[0] = (bf16)a[0];  o[1] = (bf16)a[1];  o[2] = (bf16)a[2];  o[3] = (bf16)a[3];
    o[4] = (bf16)bb[0]; o[5] = (bf16)bb[1]; o[6] = (bf16)bb[2]; o[7] = (bf16)bb[3];
    *((bf16x8*)dst + i) = o;
  } else {
    if (t < 4) firstv[t] = S_LEN;
    __syncthreads();
    for (int i = t; i < S_LEN; i += 256) {
      int s = seg[i];
      if (i == 0 || seg[i - 1] != s) atomicMin(&firstv[s], i);
    }
    __syncthreads();
    if (t < 32) {
      int smin = seg[t * 64], smax = seg[t * 64 + 63];
      int lb = S_LEN, ub = S_LEN;
      for (int vv = smin; vv < 4; ++vv) lb = min(lb, firstv[vv]);
      for (int vv = smax + 1; vv < 4; ++vv) ub = min(ub, firstv[vv]);
      kbr[t * 2] = lb >> 6;
      kbr[t * 2 + 1] = (ub - 1) >> 6;  // inclusive
    }
  }
}

// ---------------------------------------------------------------------------
// QKV GEMM (R9 — measured best): 128x64 tile, BK=128 via four split 32-k
// LDS arrays (48KB, 3 blocks/CU), DMA staging, 2-barrier K-loop. Epilogue
// by z: z=0 rope*0.125 -> q0; z=1 rope -> k0; z=2 transposed store -> Vt.
__global__ __launch_bounds__(256) void gemm_qkv(
    const bf16* __restrict__ A,
    const bf16* __restrict__ B0, const bf16* __restrict__ B1,
    const bf16* __restrict__ B2,
    const float* __restrict__ cosT, const float* __restrict__ sinT,
    bf16* __restrict__ Cbase, bf16* __restrict__ Vt)
{
  constexpr int K = 1024, N = 1024;
  const int z = blockIdx.z;
  const bf16* W = (z == 0) ? B0 : (z == 1) ? B1 : B2;
  bf16* C = Cbase + (size_t)z * 2048 * 1024;

  __shared__ bf16 As[4][128 * 32] __attribute__((aligned(16)));  // 32KB
  __shared__ bf16 Bs[4][64 * 32] __attribute__((aligned(16)));   // 16KB

  const int t = threadIdx.x;
  const int lane = t & 63;
  const int w = t >> 6;
  const int lm = lane & 15, lq = lane >> 4;
  const int wr = w >> 1, wc = w & 1;
  const int bm = blockIdx.y, bn = blockIdx.x;

  const bf16* Abase = A + (size_t)bm * 128 * K;
  const bf16* Wbase = W + (size_t)bn * 64 * K;

  f32x4 acc[4][2] = {};

  for (int kk = 0; kk < K; kk += 128) {
#pragma unroll
    for (int kh = 0; kh < 2; ++kh)
#pragma unroll
      for (int g = 0; g < 2; ++g) {
        int c = (w * 2 + g) * 64 + lane;
        int row = c >> 2, k8 = c & 3;
        const bf16* ga = Abase + (size_t)row * K + kk + kh * 64 + k8 * 8;
        async_cp16(ga, &As[kh * 2][(w * 2 + g) * 512]);
        async_cp16(ga + 32, &As[kh * 2 + 1][(w * 2 + g) * 512]);
      }
#pragma unroll
    for (int kh = 0; kh < 2; ++kh) {
      int c = w * 64 + lane;
      int row = c >> 2, k8 = c & 3;
      const bf16* gb = Wbase + (size_t)row * K + kk + kh * 64 + k8 * 8;
      async_cp16(gb, &Bs[kh * 2][w * 512]);
      async_cp16(gb + 32, &Bs[kh * 2 + 1][w * 512]);
    }
    __syncthreads();

#pragma unroll
    for (int ks = 0; ks < 4; ++ks) {
      bf16x8 af[4], bfr[2];
#pragma unroll
      for (int mi = 0; mi < 4; ++mi)
        af[mi] = *(const bf16x8*)&As[ks][(wr * 64 + mi * 16 + lm) * 32 + lq * 8];
#pragma unroll
      for (int ni = 0; ni < 2; ++ni)
        bfr[ni] = *(const bf16x8*)&Bs[ks][(wc * 32 + ni * 16 + lm) * 32 + lq * 8];
#pragma unroll
      for (int mi = 0; mi < 4; ++mi)
#pragma unroll
        for (int ni = 0; ni < 2; ++ni)
          acc[mi][ni] = __builtin_amdgcn_mfma_f32_16x16x32_bf16(
              af[mi], bfr[ni], acc[mi][ni], 0, 0, 0);
    }
    __syncthreads();
  }

  // C/D layout: col = lane&15, row = (lane>>4)*4 + reg (m89/m91-verified)
  if (z < 2) {
    const float scale = (z == 0) ? 0.125f : 1.0f;  // 1/sqrt(DH) folded into q
#pragma unroll
    for (int mi = 0; mi < 4; ++mi)
#pragma unroll
      for (int ni = 0; ni < 2; ++ni) {
        int gcol = bn * 64 + wc * 32 + ni * 16 + lm;
        int p = (gcol & 63) >> 1;
        bool even = (gcol & 1) == 0;
#pragma unroll
        for (int r = 0; r < 4; ++r) {
          int row = bm * 128 + wr * 64 + mi * 16 + lq * 4 + r;
          float v = acc[mi][ni][r];
          float mate = __shfl_xor(v, 1);   // partner col of the rope pair
          float cv = cosT[row * 32 + p];
          float sv = sinT[row * 32 + p];
          float res = even ? (v * cv - mate * sv) : (mate * sv + v * cv);
          C[(size_t)row * N + gcol] = (bf16)(res * scale);
        }
      }
  } else {
#pragma unroll
    for (int mi = 0; mi < 4; ++mi)
#pragma unroll
      for (int ni = 0; ni < 2; ++ni) {
        int gcol = bn * 64 + wc * 32 + ni * 16 + lm;      // d index
        int rowb = bm * 128 + wr * 64 + mi * 16 + lq * 4; // s index base
        bf16x4 pack;
#pragma unroll
        for (int r = 0; r < 4; ++r) pack[r] = (bf16)acc[mi][ni][r];
        *(bf16x4*)(Vt + (size_t)gcol * S_LEN + rowb) = pack;
      }
  }
}

// ---------------------------------------------------------------------------
// Output GEMM (R11): out = (combine(Opar)/l) @ Wo^T fused — the combine_k
// kernel is folded into the A-tile staging. 64x64 tile, BK=128, B via DMA,
// A via reg-staged par-sum * 1/l (Linv[16][64] precomputed in prologue).
__global__ __launch_bounds__(256) void gemm_wo(
    const f16* __restrict__ Opar, const float* __restrict__ Lpar,
    const bf16* __restrict__ W, float* __restrict__ C)
{
  constexpr int K = 1024, N = 1024;
  const size_t PO = (size_t)NHEAD * S_LEN * DHEAD;  // par stride (elems)
  const size_t PL = (size_t)NHEAD * S_LEN;

  __shared__ bf16 As[4][64 * 32] __attribute__((aligned(16)));
  __shared__ bf16 Bs[4][64 * 32] __attribute__((aligned(16)));
  __shared__ float Linv[NHEAD][64];  // 4KB: 1/(l0+l1) per (head, row)

  const int t = threadIdx.x;
  const int lane = t & 63;
  const int w = t >> 6;
  const int lm = lane & 15, lq = lane >> 4;
  const int bn = blockIdx.x, bm = blockIdx.y;

  const bf16* Wbase = W + (size_t)bn * 64 * K;

  // prologue: denominators for this row-block (16 heads x 64 rows)
  for (int i = t; i < NHEAD * 64; i += 256) {
    int h = i >> 6, row = i & 63;
    size_t li = (size_t)h * S_LEN + bm * 64 + row;
    Linv[h][row] = 1.0f / (Lpar[li] + Lpar[PL + li]);
  }
  __syncthreads();

  f32x4 acc[4] = {};

  for (int kk = 0; kk < K; kk += 128) {
    // B staging via DMA (unchanged)
#pragma unroll
    for (int kh = 0; kh < 2; ++kh) {
      int c = w * 64 + lane;
      int row = c >> 2, k8 = c & 3;
      const bf16* gb = Wbase + (size_t)row * K + kk + kh * 64 + k8 * 8;
      async_cp16(gb, &Bs[kh * 2][w * 512]);
      async_cp16(gb + 32, &Bs[kh * 2 + 1][w * 512]);
    }
    // A staging fused with combine: 4 passes x 8 bf16 per thread
#pragma unroll
    for (int p = 0; p < 4; ++p) {
      int id = p * 256 + t;
      int row = id >> 4, ch = id & 15;     // row in tile, 8-elem k-chunk
      int col = kk + ch * 8;
      int h = col >> 6, d = col & 63;
      const f16* o0 = Opar + ((size_t)h * S_LEN + bm * 64 + row) * DHEAD + d;
      f16x4 a0 = *(const f16x4*)o0;
      f16x4 a1 = *(const f16x4*)(o0 + 4);
      f16x4 b0 = *(const f16x4*)(o0 + PO);
      f16x4 b1 = *(const f16x4*)(o0 + PO + 4);
      float inv = Linv[h][row];
      bf16x8 pk;
#pragma unroll
      for (int j = 0; j < 4; ++j) {
        pk[j]     = (bf16)(((float)a0[j] + (float)b0[j]) * inv);
        pk[4 + j] = (bf16)(((float)a1[j] + (float)b1[j]) * inv);
      }
      *(bf16x8*)&As[ch >> 2][row * 32 + (ch & 3) * 8] = pk;
    }
    __syncthreads();

#pragma unroll
    for (int ks = 0; ks < 4; ++ks) {
      bf16x8 af = *(const bf16x8*)&As[ks][(w * 16 + lm) * 32 + lq * 8];
      bf16x8 bfr[4];
#pragma unroll
      for (int ni = 0; ni < 4; ++ni)
        bfr[ni] = *(const bf16x8*)&Bs[ks][(ni * 16 + lm) * 32 + lq * 8];
#pragma unroll
      for (int ni = 0; ni < 4; ++ni)
        acc[ni] = __builtin_amdgcn_mfma_f32_16x16x32_bf16(
            af, bfr[ni], acc[ni], 0, 0, 0);
    }
    __syncthreads();
  }

#pragma unroll
  for (int ni = 0; ni < 4; ++ni) {
    int col = bn * 64 + ni * 16 + lm;
#pragma unroll
    for (int r = 0; r < 4; ++r) {
      int row = bm * 64 + w * 16 + lq * 4 + r;
      C[(size_t)row * N + col] = acc[ni][r];
    }
  }
}

// ---------------------------------------------------------------------------
// Flash attention (R10 structure + R11 setprio): Q-tile 128, 8 waves,
// no-max softmax, split-K x2 (blockIdx.x = par*16 + qt). Partials: O f16,
// l fp32. kbr per-64-row: lb(128-tile)=kbr[4qt], ub=kbr[4qt+3].
__global__ __launch_bounds__(512, 4) void attn_k(
    const bf16* __restrict__ Q, const bf16* __restrict__ Kmat,
    const bf16* __restrict__ Vt, const int* __restrict__ seg,
    const int* __restrict__ kbr,
    f16* __restrict__ Opar, float* __restrict__ Lpar)
{
  __shared__ bf16 Ks[64 * 72] __attribute__((aligned(16)));    // [key][dh]
  __shared__ bf16 Vs[64 * 72] __attribute__((aligned(16)));    // [dh][key]
  __shared__ bf16 Ps[8][16 * 72] __attribute__((aligned(16))); // per-wave P
  __shared__ int segk[64];

  const int h = blockIdx.y;
  const int qt = blockIdx.x & 15, par = blockIdx.x >> 4;
  const int q0 = qt * 128;
  const int t = threadIdx.x, lane = t & 63, w = t >> 6;
  const int lm = lane & 15, lq = lane >> 4;
  const int qrow = q0 + w * 16;

  const int kb0f = kbr[qt * 4], kb1f = kbr[qt * 4 + 3];  // inclusive

  bf16x8 qf[2];  // A-operand: m = lane&15, k = quad*8+j
#pragma unroll
  for (int ks = 0; ks < 2; ++ks)
    qf[ks] = *(const bf16x8*)(Q + (size_t)(qrow + lm) * D_DIM + h * DHEAD +
                              ks * 32 + lq * 8);

  int sq[4];
  float l_i[4];  // per-LANE partials (reduced once at the end)
#pragma unroll
  for (int r = 0; r < 4; ++r) {
    sq[r] = seg[qrow + lq * 4 + r];
    l_i[r] = 0.0f;
  }
  f32x4 o[4] = {};

  const int srow0 = t >> 3, sch = (t & 7) * 8;  // 512 thr: one 16B chunk each

  const int kbS = kb0f + par;
  f32x4 pk0, pv0;
  int psg;
  if (kbS <= kb1f) {
    const int k0 = kbS * 64;
    pk0 = *(const f32x4*)(Kmat + (size_t)(k0 + srow0) * D_DIM + h * DHEAD + sch);
    pv0 = *(const f32x4*)(Vt + (size_t)(h * DHEAD + srow0) * S_LEN + k0 + sch);
    if (t < 64) psg = seg[k0 + t];
  }

  for (int kb = kbS; kb <= kb1f; kb += NPAR) {
    __syncthreads();
    *(f32x4*)&Ks[srow0 * 72 + sch] = pk0;
    *(f32x4*)&Vs[srow0 * 72 + sch] = pv0;
    if (t < 64) segk[t] = psg;
    __syncthreads();

    if (kb + NPAR <= kb1f) {  // prefetch next assigned tile (uniform branch)
      const int k0 = (kb + NPAR) * 64;
      pk0 = *(const f32x4*)(Kmat + (size_t)(k0 + srow0) * D_DIM + h * DHEAD + sch);
      pv0 = *(const f32x4*)(Vt + (size_t)(h * DHEAD + srow0) * S_LEN + k0 + sch);
      if (t < 64) psg = seg[k0 + t];
    }

    // S = Q K^T (Q pre-scaled by 1/sqrt(DH) in the QKV epilogue)
    f32x4 sa[4] = {};
    __builtin_amdgcn_s_setprio(1);
#pragma unroll
    for (int ks = 0; ks < 2; ++ks) {
      bf16x8 kf[4];
#pragma unroll
      for (int ni = 0; ni < 4; ++ni)
        kf[ni] = *(const bf16x8*)&Ks[(ni * 16 + lm) * 72 + ks * 32 + lq * 8];
#pragma unroll
      for (int ni = 0; ni < 4; ++ni)
        sa[ni] = __builtin_amdgcn_mfma_f32_16x16x32_bf16(qf[ks], kf[ni],
                                                         sa[ni], 0, 0, 0);
    }
    __builtin_amdgcn_s_setprio(0);

    int sk[4];
#pragma unroll
    for (int ni = 0; ni < 4; ++ni) sk[ni] = segk[ni * 16 + lm];

#pragma unroll
    for (int r = 0; r < 4; ++r)
#pragma unroll
      for (int ni = 0; ni < 4; ++ni) {
        float p = (sq[r] == sk[ni]) ? __expf(sa[ni][r]) : 0.0f;
        l_i[r] += p;
        Ps[w][(lq * 4 + r) * 72 + ni * 16 + lm] = (bf16)p;
      }

    // O += P @ V
    __builtin_amdgcn_s_setprio(1);
#pragma unroll
    for (int ks = 0; ks < 2; ++ks) {
      bf16x8 pf = *(const bf16x8*)&Ps[w][lm * 72 + ks * 32 + lq * 8];
      bf16x8 vf[4];
#pragma unroll
      for (int ni = 0; ni < 4; ++ni)
        vf[ni] = *(const bf16x8*)&Vs[(ni * 16 + lm) * 72 + ks * 32 + lq * 8];
#pragma unroll
      for (int ni = 0; ni < 4; ++ni)
        o[ni] = __builtin_amdgcn_mfma_f32_16x16x32_bf16(pf, vf[ni], o[ni],
                                                        0, 0, 0);
    }
    __builtin_amdgcn_s_setprio(0);
  }

  f16* Ob = Opar + ((size_t)(par * NHEAD + h) * S_LEN) * DHEAD;
  float* Lb = Lpar + (size_t)(par * NHEAD + h) * S_LEN;
#pragma unroll
  for (int r = 0; r < 4; ++r) {
    float l = l_i[r];
    l += __shfl_xor(l, 1);
    l += __shfl_xor(l, 2);
    l += __shfl_xor(l, 4);
    l += __shfl_xor(l, 8);
    int row = qrow + lq * 4 + r;
    if (lm == 0) Lb[row] = l;
#pragma unroll
    for (int ni = 0; ni < 4; ++ni)
      Ob[(size_t)row * DHEAD + ni * 16 + lm] = (f16)o[ni][r];
  }
}

// ---------------------------------------------------------------------------
extern "C" void kernel_launch(void* const* d_in, const int* in_sizes, int n_in,
                              void* d_out, int out_size, void* d_ws,
                              size_t ws_size, hipStream_t stream)
{
  const float* x  = (const float*)d_in[0];
  const int*   sg = (const int*)d_in[1];
  const float* fc = (const float*)d_in[2];
  const float* fs = (const float*)d_in[3];
  const float* wq = (const float*)d_in[4];
  const float* wk = (const float*)d_in[5];
  const float* wv = (const float*)d_in[6];
  const float* wo = (const float*)d_in[7];
  float* out = (float*)d_out;

  const size_t MAT = (size_t)S_LEN * D_DIM;  // 2M elements
  const size_t WSZ = (size_t)D_DIM * D_DIM;  // 1M elements
  bf16* xb  = (bf16*)d_ws;         // cvt_k writes xb..wob contiguous
  bf16* wqb = xb + MAT;
  bf16* wkb = wqb + WSZ;
  bf16* wvb = wkb + WSZ;
  bf16* wob = wvb + WSZ;
  bf16* q0  = wob + WSZ;           // rope'd+scaled, by gemm_qkv z=0
  bf16* k0  = q0 + MAT;            // rope'd, by gemm_qkv z=1
  bf16* vt  = k0 + MAT;            // V^T [1024][2048], by gemm_qkv z=2
  f16*  opar = (f16*)(vt + MAT);             // NPAR x 16 x 2048 x 64 f16
  float* lpar = (float*)(opar + (size_t)NPAR * MAT);  // NPAR x 16 x 2048 f32
  int*   kbr  = (int*)(lpar + (size_t)NPAR * NHEAD * S_LEN);  // 32 x 2

  dim3 blk(256);
  cvt_k<<<dim3(3073), blk, 0, stream>>>(x, wq, wk, wv, wo, xb, sg, kbr);
  gemm_qkv<<<dim3(16, 16, 3), blk, 0, stream>>>(xb, wqb, wkb, wvb, fc, fs,
                                                q0, vt);
  attn_k<<<dim3(16 * NPAR, 16), dim3(512), 0, stream>>>(q0, k0, vt, sg, kbr,
                                                        opar, lpar);
  gemm_wo<<<dim3(16, 32), blk, 0, stream>>>(opar, lpar, wob, out);
}

// Round 3
// 136.775 us; speedup vs baseline: 1.0782x; 1.0782x over previous
//
#include <hip/hip_runtime.h>

typedef __bf16 bf16;
typedef __bf16 bf16x4 __attribute__((ext_vector_type(4)));
typedef __bf16 bf16x8 __attribute__((ext_vector_type(8)));
typedef float  f32x4  __attribute__((ext_vector_type(4)));

#define S_LEN 2048
#define D_DIM 1024
#define NHEAD 16
#define DHEAD 64

// ---------------------------------------------------------------------------
// async global->LDS, 16B per lane (wave-uniform LDS base + lane*16, m104).
__device__ __forceinline__ void async_cp16(const bf16* g, bf16* l) {
  __builtin_amdgcn_global_load_lds(
      (__attribute__((address_space(1))) void*)(void*)g,
      (__attribute__((address_space(3))) void*)l,
      16, 0, 0);
}

// ---------------------------------------------------------------------------
// fp32 -> bf16 cvt of x + 4 weights (blocks [0,3072)); block 3072 computes
// per-Q-tile key-block ranges kbr[32][2] from sorted seg_ids.
__global__ __launch_bounds__(256) void cvt_k(
    const float* __restrict__ x,  const float* __restrict__ w0,
    const float* __restrict__ w1, const float* __restrict__ w2,
    const float* __restrict__ w3, bf16* __restrict__ dst,
    const int* __restrict__ seg, int* __restrict__ kbr)
{
  __shared__ int firstv[4];
  const int b = blockIdx.x;
  const int t = threadIdx.x;

  if (b < 3072) {
    int i = b * 256 + t;  // 0 .. 786431 (x8 elems)
    const float* src;
    int off;
    if (i < (1 << 18)) {            // x: 2^18 groups of 8
      src = x; off = i;
    } else {
      int j = i - (1 << 18);        // weights: 2^17 groups each
      int s = j >> 17;
      off = j & ((1 << 17) - 1);
      src = (s == 0) ? w0 : (s == 1) ? w1 : (s == 2) ? w2 : w3;
    }
    f32x4 a = *(const f32x4*)(src + (size_t)off * 8);
    f32x4 bb = *(const f32x4*)(src + (size_t)off * 8 + 4);
    bf16x8 o;
    o[0] = (bf16)a[0];  o[1] = (bf16)a[1];  o[2] = (bf16)a[2];  o[3] = (bf16)a[3];
    o[4] = (bf16)bb[0]; o[5] = (bf16)bb[1]; o[6] = (bf16)bb[2]; o[7] = (bf16)bb[3];
    *((bf16x8*)dst + i) = o;
  } else {
    if (t < 4) firstv[t] = S_LEN;
    __syncthreads();
    for (int i = t; i < S_LEN; i += 256) {
      int s = seg[i];
      if (i == 0 || seg[i - 1] != s) atomicMin(&firstv[s], i);
    }
    __syncthreads();
    if (t < 32) {
      int smin = seg[t * 64], smax = seg[t * 64 + 63];
      int lb = S_LEN, ub = S_LEN;
      for (int vv = smin; vv < 4; ++vv) lb = min(lb, firstv[vv]);
      for (int vv = smax + 1; vv < 4; ++vv) ub = min(ub, firstv[vv]);
      kbr[t * 2] = lb >> 6;
      kbr[t * 2 + 1] = (ub - 1) >> 6;  // inclusive
    }
  }
}

// ---------------------------------------------------------------------------
// QKV GEMM (R9 — measured best): 128x64 tile, BK=128 via four split 32-k
// LDS arrays (48KB, 3 blocks/CU), DMA staging, 2-barrier K-loop. Epilogue
// by z: z=0 rope*0.125 -> q0; z=1 rope -> k0; z=2 transposed store -> Vt.
__global__ __launch_bounds__(256) void gemm_qkv(
    const bf16* __restrict__ A,
    const bf16* __restrict__ B0, const bf16* __restrict__ B1,
    const bf16* __restrict__ B2,
    const float* __restrict__ cosT, const float* __restrict__ sinT,
    bf16* __restrict__ Cbase, bf16* __restrict__ Vt)
{
  constexpr int K = 1024, N = 1024;
  const int z = blockIdx.z;
  const bf16* W = (z == 0) ? B0 : (z == 1) ? B1 : B2;
  bf16* C = Cbase + (size_t)z * 2048 * 1024;

  __shared__ bf16 As[4][128 * 32] __attribute__((aligned(16)));  // 32KB
  __shared__ bf16 Bs[4][64 * 32] __attribute__((aligned(16)));   // 16KB

  const int t = threadIdx.x;
  const int lane = t & 63;
  const int w = t >> 6;
  const int lm = lane & 15, lq = lane >> 4;
  const int wr = w >> 1, wc = w & 1;
  const int bm = blockIdx.y, bn = blockIdx.x;

  const bf16* Abase = A + (size_t)bm * 128 * K;
  const bf16* Wbase = W + (size_t)bn * 64 * K;

  f32x4 acc[4][2] = {};

  for (int kk = 0; kk < K; kk += 128) {
#pragma unroll
    for (int kh = 0; kh < 2; ++kh)
#pragma unroll
      for (int g = 0; g < 2; ++g) {
        int c = (w * 2 + g) * 64 + lane;
        int row = c >> 2, k8 = c & 3;
        const bf16* ga = Abase + (size_t)row * K + kk + kh * 64 + k8 * 8;
        async_cp16(ga, &As[kh * 2][(w * 2 + g) * 512]);
        async_cp16(ga + 32, &As[kh * 2 + 1][(w * 2 + g) * 512]);
      }
#pragma unroll
    for (int kh = 0; kh < 2; ++kh) {
      int c = w * 64 + lane;
      int row = c >> 2, k8 = c & 3;
      const bf16* gb = Wbase + (size_t)row * K + kk + kh * 64 + k8 * 8;
      async_cp16(gb, &Bs[kh * 2][w * 512]);
      async_cp16(gb + 32, &Bs[kh * 2 + 1][w * 512]);
    }
    __syncthreads();

#pragma unroll
    for (int ks = 0; ks < 4; ++ks) {
      bf16x8 af[4], bfr[2];
#pragma unroll
      for (int mi = 0; mi < 4; ++mi)
        af[mi] = *(const bf16x8*)&As[ks][(wr * 64 + mi * 16 + lm) * 32 + lq * 8];
#pragma unroll
      for (int ni = 0; ni < 2; ++ni)
        bfr[ni] = *(const bf16x8*)&Bs[ks][(wc * 32 + ni * 16 + lm) * 32 + lq * 8];
#pragma unroll
      for (int mi = 0; mi < 4; ++mi)
#pragma unroll
        for (int ni = 0; ni < 2; ++ni)
          acc[mi][ni] = __builtin_amdgcn_mfma_f32_16x16x32_bf16(
              af[mi], bfr[ni], acc[mi][ni], 0, 0, 0);
    }
    __syncthreads();
  }

  // C/D layout: col = lane&15, row = (lane>>4)*4 + reg (m89/m91-verified)
  if (z < 2) {
    const float scale = (z == 0) ? 0.125f : 1.0f;  // 1/sqrt(DH) folded into q
#pragma unroll
    for (int mi = 0; mi < 4; ++mi)
#pragma unroll
      for (int ni = 0; ni < 2; ++ni) {
        int gcol = bn * 64 + wc * 32 + ni * 16 + lm;
        int p = (gcol & 63) >> 1;
        bool even = (gcol & 1) == 0;
#pragma unroll
        for (int r = 0; r < 4; ++r) {
          int row = bm * 128 + wr * 64 + mi * 16 + lq * 4 + r;
          float v = acc[mi][ni][r];
          float mate = __shfl_xor(v, 1);   // partner col of the rope pair
          float cv = cosT[row * 32 + p];
          float sv = sinT[row * 32 + p];
          float res = even ? (v * cv - mate * sv) : (mate * sv + v * cv);
          C[(size_t)row * N + gcol] = (bf16)(res * scale);
        }
      }
  } else {
#pragma unroll
    for (int mi = 0; mi < 4; ++mi)
#pragma unroll
      for (int ni = 0; ni < 2; ++ni) {
        int gcol = bn * 64 + wc * 32 + ni * 16 + lm;      // d index
        int rowb = bm * 128 + wr * 64 + mi * 16 + lq * 4; // s index base
        bf16x4 pack;
#pragma unroll
        for (int r = 0; r < 4; ++r) pack[r] = (bf16)acc[mi][ni][r];
        *(bf16x4*)(Vt + (size_t)gcol * S_LEN + rowb) = pack;
      }
  }
}

// ---------------------------------------------------------------------------
// Output GEMM (R10 — measured best): out = ao @ Wo^T, 64x64 tile, BK=128,
// DMA staging, 2-barrier K-loop, fp32 direct store.
__global__ __launch_bounds__(256) void gemm_wo(
    const bf16* __restrict__ A, const bf16* __restrict__ W,
    float* __restrict__ C)
{
  constexpr int K = 1024, N = 1024;

  __shared__ bf16 As[4][64 * 32] __attribute__((aligned(16)));
  __shared__ bf16 Bs[4][64 * 32] __attribute__((aligned(16)));

  const int t = threadIdx.x;
  const int lane = t & 63;
  const int w = t >> 6;
  const int lm = lane & 15, lq = lane >> 4;
  const int bn = blockIdx.x, bm = blockIdx.y;

  const bf16* Abase = A + (size_t)bm * 64 * K;
  const bf16* Wbase = W + (size_t)bn * 64 * K;

  f32x4 acc[4] = {};

  for (int kk = 0; kk < K; kk += 128) {
#pragma unroll
    for (int kh = 0; kh < 2; ++kh) {
      int c = w * 64 + lane;
      int row = c >> 2, k8 = c & 3;
      const bf16* ga = Abase + (size_t)row * K + kk + kh * 64 + k8 * 8;
      async_cp16(ga, &As[kh * 2][w * 512]);
      async_cp16(ga + 32, &As[kh * 2 + 1][w * 512]);
      const bf16* gb = Wbase + (size_t)row * K + kk + kh * 64 + k8 * 8;
      async_cp16(gb, &Bs[kh * 2][w * 512]);
      async_cp16(gb + 32, &Bs[kh * 2 + 1][w * 512]);
    }
    __syncthreads();

#pragma unroll
    for (int ks = 0; ks < 4; ++ks) {
      bf16x8 af = *(const bf16x8*)&As[ks][(w * 16 + lm) * 32 + lq * 8];
      bf16x8 bfr[4];
#pragma unroll
      for (int ni = 0; ni < 4; ++ni)
        bfr[ni] = *(const bf16x8*)&Bs[ks][(ni * 16 + lm) * 32 + lq * 8];
#pragma unroll
      for (int ni = 0; ni < 4; ++ni)
        acc[ni] = __builtin_amdgcn_mfma_f32_16x16x32_bf16(
            af, bfr[ni], acc[ni], 0, 0, 0);
    }
    __syncthreads();
  }

#pragma unroll
  for (int ni = 0; ni < 4; ++ni) {
    int col = bn * 64 + ni * 16 + lm;
#pragma unroll
    for (int r = 0; r < 4; ++r) {
      int row = bm * 64 + w * 16 + lq * 4 + r;
      C[(size_t)row * N + col] = acc[ni][r];
    }
  }
}

// ---------------------------------------------------------------------------
// Flash attention (R12): Q-tile 128, 8 waves (512 threads), no split-K —
// each (qt,h) block owns its full key range (avg ~8-9 tiles, max ~16), so
// the denominator is complete in-block and the epilogue writes normalized
// bf16 ao directly (combine stage + Opar/Lpar round-trip eliminated).
// Grid 16x16 = 256 blocks = 1/CU, fully co-resident. setprio around MFMA
// clusters (m191). kbr per-64-row: lb(128-tile)=kbr[4qt], ub=kbr[4qt+3].
__global__ __launch_bounds__(512, 2) void attn_k(
    const bf16* __restrict__ Q, const bf16* __restrict__ Kmat,
    const bf16* __restrict__ Vt, const int* __restrict__ seg,
    const int* __restrict__ kbr,
    bf16* __restrict__ AO)
{
  __shared__ bf16 Ks[64 * 72] __attribute__((aligned(16)));    // [key][dh]
  __shared__ bf16 Vs[64 * 72] __attribute__((aligned(16)));    // [dh][key]
  __shared__ bf16 Ps[8][16 * 72] __attribute__((aligned(16))); // per-wave P
  __shared__ int segk[64];

  const int h = blockIdx.y;
  const int qt = blockIdx.x;
  const int q0 = qt * 128;
  const int t = threadIdx.x, lane = t & 63, w = t >> 6;
  const int lm = lane & 15, lq = lane >> 4;
  const int qrow = q0 + w * 16;

  const int kb0f = kbr[qt * 4], kb1f = kbr[qt * 4 + 3];  // inclusive

  bf16x8 qf[2];  // A-operand: m = lane&15, k = quad*8+j
#pragma unroll
  for (int ks = 0; ks < 2; ++ks)
    qf[ks] = *(const bf16x8*)(Q + (size_t)(qrow + lm) * D_DIM + h * DHEAD +
                              ks * 32 + lq * 8);

  int sq[4];
  float l_i[4];  // per-LANE partials (reduced once at the end)
#pragma unroll
  for (int r = 0; r < 4; ++r) {
    sq[r] = seg[qrow + lq * 4 + r];
    l_i[r] = 0.0f;
  }
  f32x4 o[4] = {};

  const int srow0 = t >> 3, sch = (t & 7) * 8;  // 512 thr: one 16B chunk each

  f32x4 pk0, pv0;
  int psg;
  {
    const int k0 = kb0f * 64;
    pk0 = *(const f32x4*)(Kmat + (size_t)(k0 + srow0) * D_DIM + h * DHEAD + sch);
    pv0 = *(const f32x4*)(Vt + (size_t)(h * DHEAD + srow0) * S_LEN + k0 + sch);
    if (t < 64) psg = seg[k0 + t];
  }

  for (int kb = kb0f; kb <= kb1f; ++kb) {
    __syncthreads();
    *(f32x4*)&Ks[srow0 * 72 + sch] = pk0;
    *(f32x4*)&Vs[srow0 * 72 + sch] = pv0;
    if (t < 64) segk[t] = psg;
    __syncthreads();

    if (kb + 1 <= kb1f) {  // prefetch next tile (uniform branch)
      const int k0 = (kb + 1) * 64;
      pk0 = *(const f32x4*)(Kmat + (size_t)(k0 + srow0) * D_DIM + h * DHEAD + sch);
      pv0 = *(const f32x4*)(Vt + (size_t)(h * DHEAD + srow0) * S_LEN + k0 + sch);
      if (t < 64) psg = seg[k0 + t];
    }

    // S = Q K^T (Q pre-scaled by 1/sqrt(DH) in the QKV epilogue)
    f32x4 sa[4] = {};
    __builtin_amdgcn_s_setprio(1);
#pragma unroll
    for (int ks = 0; ks < 2; ++ks) {
      bf16x8 kf[4];
#pragma unroll
      for (int ni = 0; ni < 4; ++ni)
        kf[ni] = *(const bf16x8*)&Ks[(ni * 16 + lm) * 72 + ks * 32 + lq * 8];
#pragma unroll
      for (int ni = 0; ni < 4; ++ni)
        sa[ni] = __builtin_amdgcn_mfma_f32_16x16x32_bf16(qf[ks], kf[ni],
                                                         sa[ni], 0, 0, 0);
    }
    __builtin_amdgcn_s_setprio(0);

    int sk[4];
#pragma unroll
    for (int ni = 0; ni < 4; ++ni) sk[ni] = segk[ni * 16 + lm];

#pragma unroll
    for (int r = 0; r < 4; ++r)
#pragma unroll
      for (int ni = 0; ni < 4; ++ni) {
        float p = (sq[r] == sk[ni]) ? __expf(sa[ni][r]) : 0.0f;
        l_i[r] += p;
        Ps[w][(lq * 4 + r) * 72 + ni * 16 + lm] = (bf16)p;
      }

    // O += P @ V
    __builtin_amdgcn_s_setprio(1);
#pragma unroll
    for (int ks = 0; ks < 2; ++ks) {
      bf16x8 pf = *(const bf16x8*)&Ps[w][lm * 72 + ks * 32 + lq * 8];
      bf16x8 vf[4];
#pragma unroll
      for (int ni = 0; ni < 4; ++ni)
        vf[ni] = *(const bf16x8*)&Vs[(ni * 16 + lm) * 72 + ks * 32 + lq * 8];
#pragma unroll
      for (int ni = 0; ni < 4; ++ni)
        o[ni] = __builtin_amdgcn_mfma_f32_16x16x32_bf16(pf, vf[ni], o[ni],
                                                        0, 0, 0);
    }
    __builtin_amdgcn_s_setprio(0);
  }

  // epilogue: full denominator in-block -> normalize and store final bf16
#pragma unroll
  for (int r = 0; r < 4; ++r) {
    float l = l_i[r];
    l += __shfl_xor(l, 1);
    l += __shfl_xor(l, 2);
    l += __shfl_xor(l, 4);
    l += __shfl_xor(l, 8);
    float inv = 1.0f / l;
    int row = qrow + lq * 4 + r;
#pragma unroll
    for (int ni = 0; ni < 4; ++ni)
      AO[(size_t)row * D_DIM + h * DHEAD + ni * 16 + lm] =
          (bf16)(o[ni][r] * inv);
  }
}

// ---------------------------------------------------------------------------
extern "C" void kernel_launch(void* const* d_in, const int* in_sizes, int n_in,
                              void* d_out, int out_size, void* d_ws,
                              size_t ws_size, hipStream_t stream)
{
  const float* x  = (const float*)d_in[0];
  const int*   sg = (const int*)d_in[1];
  const float* fc = (const float*)d_in[2];
  const float* fs = (const float*)d_in[3];
  const float* wq = (const float*)d_in[4];
  const float* wk = (const float*)d_in[5];
  const float* wv = (const float*)d_in[6];
  const float* wo = (const float*)d_in[7];
  float* out = (float*)d_out;

  const size_t MAT = (size_t)S_LEN * D_DIM;  // 2M elements
  const size_t WSZ = (size_t)D_DIM * D_DIM;  // 1M elements
  bf16* xb  = (bf16*)d_ws;         // cvt_k writes xb..wob contiguous
  bf16* wqb = xb + MAT;
  bf16* wkb = wqb + WSZ;
  bf16* wvb = wkb + WSZ;
  bf16* wob = wvb + WSZ;
  bf16* q0  = wob + WSZ;           // rope'd+scaled, by gemm_qkv z=0
  bf16* k0  = q0 + MAT;            // rope'd, by gemm_qkv z=1
  bf16* vt  = k0 + MAT;            // V^T [1024][2048], by gemm_qkv z=2
  bf16* ao  = vt + MAT;            // normalized attention output (bf16)
  int*  kbr = (int*)(ao + MAT);    // 32 x 2

  dim3 blk(256);
  cvt_k<<<dim3(3073), blk, 0, stream>>>(x, wq, wk, wv, wo, xb, sg, kbr);
  gemm_qkv<<<dim3(16, 16, 3), blk, 0, stream>>>(xb, wqb, wkb, wvb, fc, fs,
                                                q0, vt);
  attn_k<<<dim3(16, 16), dim3(512), 0, stream>>>(q0, k0, vt, sg, kbr, ao);
  gemm_wo<<<dim3(16, 32), blk, 0, stream>>>(ao, wob, out);
}